// Round 2
// baseline (16.158 us; speedup 1.0000x reference)
//
#include <hip/hip_runtime.h>

// EmbeddingDropout: out[t,:] = mask[words[t]] * weight[words[t],:]
// weight: [V=50257, D=1024] f32, mask: [V,1] f32, words: [B*S=8192] int32
// out: [8192, 1024] f32.  Pure memory-bound gather (~64 MiB traffic).
//
// Shape: one WAVE per token. 64 lanes x 16 floats (4x float4) = 1024 floats.
// 4 independent 16B loads per lane -> MLP=4 behind a single index-load chain.
// Block = 256 threads = 4 waves = 4 tokens; grid = 8192/4 = 2048 blocks.

#define DIM 1024
#define V4_PER_ROW (DIM / 4)          // 256 float4 per row
#define TOKENS_PER_BLOCK 4

__global__ void EmbeddingDropout_kernel(const float4* __restrict__ weight,
                                        const float* __restrict__ mask,
                                        const int* __restrict__ words,
                                        float4* __restrict__ out,
                                        int n_tokens) {
    int wave = threadIdx.x >> 6;                      // 0..3
    int lane = threadIdx.x & 63;
    int tok = blockIdx.x * TOKENS_PER_BLOCK + wave;
    if (tok >= n_tokens) return;

    int row = words[tok];                             // wave-uniform broadcast
    float m = mask[row];                              // wave-uniform

    const float4* __restrict__ src = weight + (size_t)row * V4_PER_ROW;
    float4*       __restrict__ dst = out    + (size_t)tok * V4_PER_ROW;

    // 4 independent coalesced 1-KiB wave transactions
    float4 v0 = src[lane];
    float4 v1 = src[lane + 64];
    float4 v2 = src[lane + 128];
    float4 v3 = src[lane + 192];

    v0.x *= m; v0.y *= m; v0.z *= m; v0.w *= m;
    v1.x *= m; v1.y *= m; v1.z *= m; v1.w *= m;
    v2.x *= m; v2.y *= m; v2.z *= m; v2.w *= m;
    v3.x *= m; v3.y *= m; v3.z *= m; v3.w *= m;

    dst[lane]       = v0;
    dst[lane + 64]  = v1;
    dst[lane + 128] = v2;
    dst[lane + 192] = v3;
}

extern "C" void kernel_launch(void* const* d_in, const int* in_sizes, int n_in,
                              void* d_out, int out_size, void* d_ws, size_t ws_size,
                              hipStream_t stream) {
    const float4* weight = (const float4*)d_in[0];
    const float*  mask   = (const float*)d_in[1];
    const int*    words  = (const int*)d_in[2];
    float4* out = (float4*)d_out;
    int n_tokens = in_sizes[2];                       // B*S = 8192

    dim3 grid((n_tokens + TOKENS_PER_BLOCK - 1) / TOKENS_PER_BLOCK);
    dim3 block(64 * TOKENS_PER_BLOCK);                // 256 threads
    EmbeddingDropout_kernel<<<grid, block, 0, stream>>>(weight, mask, words, out, n_tokens);
}

// Round 4
// 13.789 us; speedup vs baseline: 1.1717x; 1.1717x over previous
//
#include <hip/hip_runtime.h>

// EmbeddingDropout: out[t,:] = mask[words[t]] * weight[words[t],:]
// weight: [V=50257, D=1024] f32, mask: [V,1] f32, words: [B*S=8192] int32
// out: [8192, 1024] f32.  Pure memory-bound gather (~64 MiB traffic).
//
// Shape: one wave handles 2 tokens (both index chains issued up front ->
// 8 independent 16B loads in flight per wave). 4 waves/block, 8 tokens/block,
// grid = 1024. Output stored nontemporal ('nt') so the 32 MiB write stream
// doesn't evict the L3-resident weight table between graph replays.
//
// NOTE: __builtin_nontemporal_store requires a clang native vector type,
// not HIP's float4 class -> use ext_vector_type(4) float.

typedef float v4f __attribute__((ext_vector_type(4)));

#define DIM 1024
#define V4_PER_ROW (DIM / 4)          // 256 v4f per row
#define TOKENS_PER_WAVE 2
#define WAVES_PER_BLOCK 4
#define TOKENS_PER_BLOCK (TOKENS_PER_WAVE * WAVES_PER_BLOCK)

__global__ void EmbeddingDropout_kernel(const v4f* __restrict__ weight,
                                        const float* __restrict__ mask,
                                        const int* __restrict__ words,
                                        v4f* __restrict__ out,
                                        int n_tokens) {
    int wave = threadIdx.x >> 6;                      // 0..3
    int lane = threadIdx.x & 63;
    int t0 = (blockIdx.x * WAVES_PER_BLOCK + wave) * TOKENS_PER_WAVE;
    int t1 = t0 + 1;
    if (t1 >= n_tokens) {                             // tail guard (not hit at 8192)
        if (t0 >= n_tokens) return;
        t1 = t0;
    }

    // Both dependent chains issued immediately; loads are independent.
    int r0 = words[t0];
    int r1 = words[t1];
    float m0 = mask[r0];
    float m1 = mask[r1];

    const v4f* __restrict__ s0 = weight + (size_t)r0 * V4_PER_ROW;
    const v4f* __restrict__ s1 = weight + (size_t)r1 * V4_PER_ROW;

    // 8 independent coalesced 1-KiB wave transactions in flight
    v4f a0 = s0[lane];
    v4f a1 = s0[lane + 64];
    v4f a2 = s0[lane + 128];
    v4f a3 = s0[lane + 192];
    v4f b0 = s1[lane];
    v4f b1 = s1[lane + 64];
    v4f b2 = s1[lane + 128];
    v4f b3 = s1[lane + 192];

    a0 *= m0; a1 *= m0; a2 *= m0; a3 *= m0;
    b0 *= m1; b1 *= m1; b2 *= m1; b3 *= m1;

    v4f* __restrict__ d0 = out + (size_t)t0 * V4_PER_ROW;
    v4f* __restrict__ d1 = out + (size_t)t1 * V4_PER_ROW;

    __builtin_nontemporal_store(a0, d0 + lane);
    __builtin_nontemporal_store(a1, d0 + lane + 64);
    __builtin_nontemporal_store(a2, d0 + lane + 128);
    __builtin_nontemporal_store(a3, d0 + lane + 192);
    __builtin_nontemporal_store(b0, d1 + lane);
    __builtin_nontemporal_store(b1, d1 + lane + 64);
    __builtin_nontemporal_store(b2, d1 + lane + 128);
    __builtin_nontemporal_store(b3, d1 + lane + 192);
}

extern "C" void kernel_launch(void* const* d_in, const int* in_sizes, int n_in,
                              void* d_out, int out_size, void* d_ws, size_t ws_size,
                              hipStream_t stream) {
    const v4f*   weight = (const v4f*)d_in[0];
    const float* mask   = (const float*)d_in[1];
    const int*   words  = (const int*)d_in[2];
    v4f* out = (v4f*)d_out;
    int n_tokens = in_sizes[2];                       // B*S = 8192

    dim3 grid((n_tokens + TOKENS_PER_BLOCK - 1) / TOKENS_PER_BLOCK);  // 1024
    dim3 block(64 * WAVES_PER_BLOCK);                                 // 256
    EmbeddingDropout_kernel<<<grid, block, 0, stream>>>(weight, mask, words, out, n_tokens);
}